// Round 21
// baseline (187.113 us; speedup 1.0000x reference)
//
#include <hip/hip_runtime.h>
#include <hip/hip_bf16.h>
#include <math.h>

#define S_LEN 2048
#define DM    1024
#define NH    16
#define DKH   64
#define NEG_BIG (-1e30f)
// 1/sqrt(64) * log2(e), folded into Q projection so softmax runs in exp2 domain
#define QSCALE 0.18033688f

typedef __bf16 bf16_t;
typedef bf16_t bf16x8 __attribute__((ext_vector_type(8)));
typedef bf16_t bf16x4 __attribute__((ext_vector_type(4)));
typedef bf16_t bf16x2 __attribute__((ext_vector_type(2)));
typedef float  f32x4  __attribute__((ext_vector_type(4)));

__device__ __forceinline__ void gload16(const void* g, void* l) {
    __builtin_amdgcn_global_load_lds((const __attribute__((address_space(1))) void*)g,
                                     (__attribute__((address_space(3))) void*)l, 16, 0, 0);
}

__device__ __forceinline__ unsigned pack2(float a, float b) {
    bf16x2 v; v[0] = (bf16_t)a; v[1] = (bf16_t)b;
    return __builtin_bit_cast(unsigned, v);
}

__device__ __forceinline__ bf16x8 cvt8v(f32x4 a, f32x4 b) {
    bf16x8 v;
    v[0] = (bf16_t)a[0]; v[1] = (bf16_t)a[1]; v[2] = (bf16_t)a[2]; v[3] = (bf16_t)a[3];
    v[4] = (bf16_t)b[0]; v[5] = (bf16_t)b[1]; v[6] = (bf16_t)b[2]; v[7] = (bf16_t)b[3];
    return v;
}

// ---------------- weights fp32 -> bf16 (one launch, 4 matrices) ----------------
__global__ __launch_bounds__(256) void cvt4_w(const float* __restrict__ w0, const float* __restrict__ w1,
                                              const float* __restrict__ w2, const float* __restrict__ w3,
                                              bf16_t* __restrict__ o0, bf16_t* __restrict__ o1,
                                              bf16_t* __restrict__ o2, bf16_t* __restrict__ o3) {
    const float* in; bf16_t* out;
    switch (blockIdx.y) {
        case 0: in = w0; out = o0; break;
        case 1: in = w1; out = o1; break;
        case 2: in = w2; out = o2; break;
        default: in = w3; out = o3; break;
    }
    int i = (blockIdx.x * 256 + threadIdx.x) * 4;
    float4 f = *(const float4*)(in + i);
    bf16x4 v;
    v[0] = (bf16_t)f.x; v[1] = (bf16_t)f.y; v[2] = (bf16_t)f.z; v[3] = (bf16_t)f.w;
    *(bf16x4*)(out + i) = v;
}

// ---------------- projection GEMM: 128x256 tile, fp32-A, 3-deep counted vmcnt ----------------
// BN=256 halves the (expensive) fp32 A-frag LDS reads per MFMA: per wave per K-step
// 16 ds_read_b128 feed 32 MFMA (was 12 for 16). Grid 256 = 1 block/CU, 4 waves (2Mx2N).
// EPI 0: bf16 [b,h,s,d] * oscale | EPI 1: bf16 [b,h,d,s] with key-permutation A^-1
template<int EPI>
__global__ __launch_bounds__(256) void gemm_proj(const float* __restrict__ Af,
                                                 const bf16_t* __restrict__ B,
                                                 const float* __restrict__ bias,
                                                 bf16_t* __restrict__ Out,
                                                 float oscale) {
    __shared__ float  AsF[3][128 * 32];   // 48 KB fp32 A tiles, ^(row&7) 16B-slot swizzle
    __shared__ bf16_t Bs[3][256 * 32];    // 48 KB bf16 B tiles, ^(row&3) slot swizzle

    const int d    = blockIdx.x;                 // XCD = d % 8
    const int orig = (d & 7) * 32 + (d >> 3);    // orig = mB*4 + nB
    const int mBase = (orig >> 2) * 128;
    const int nBase = (orig & 3) * 256;

    const int tid  = threadIdx.x;
    const int w    = tid >> 6;
    const int lane = tid & 63;
    const int g    = lane >> 4;
    const int r    = lane & 15;
    const int wm   = w >> 1, wn = w & 1;

    const int srow = lane >> 2;
    const int scolB = (((lane & 3) ^ (srow & 3)) * 8);   // inverse-swizzled B source slot
    const int frow = lane >> 3;
    const int fsl  = (lane & 7) ^ (frow & 7);

    auto stage = [&](int buf, int kt) {   // 8 gload16 per wave
        #pragma unroll
        for (int c = 0; c < 4; ++c) {
            const int row = w * 32 + c * 8;
            gload16(Af + (size_t)(mBase + row + frow) * 1024 + kt + fsl * 4, &AsF[buf][row * 32]);
        }
        #pragma unroll
        for (int c = 0; c < 4; ++c) {
            const int row = w * 64 + c * 16;
            gload16(B + (size_t)(nBase + row + srow) * 1024 + kt + scolB, &Bs[buf][row * 32]);
        }
    };

    auto compute = [&](int buf, f32x4 (*acc)[8]) {
        bf16x8 af[4], bfr[8];
        #pragma unroll
        for (int i = 0; i < 4; i++) {
            const int R = wm * 64 + i * 16 + r;
            const float* rb = &AsF[buf][R * 32];
            f32x4 f0 = *(const f32x4*)(rb + (((2 * g) ^ (r & 7)) << 2));
            f32x4 f1 = *(const f32x4*)(rb + (((2 * g + 1) ^ (r & 7)) << 2));
            af[i] = cvt8v(f0, f1);
        }
        #pragma unroll
        for (int i = 0; i < 8; i++) {
            const int R = wn * 128 + i * 16 + r;
            bfr[i] = *(const bf16x8*)&Bs[buf][R * 32 + ((g ^ (R & 3)) * 8)];
        }
        #pragma unroll
        for (int mi = 0; mi < 4; mi++)
            #pragma unroll
            for (int ni = 0; ni < 8; ni++)
                acc[mi][ni] = __builtin_amdgcn_mfma_f32_16x16x32_bf16(
                    af[mi], bfr[ni], acc[mi][ni], 0, 0, 0);
    };

    f32x4 acc[4][8] = {};

    stage(0, 0);
    stage(1, 32);

    int cur = 0;
    for (int t = 0; t < 31; ++t) {
        asm volatile("s_waitcnt vmcnt(8)" ::: "memory");   // stage t landed; t+1 in flight
        __builtin_amdgcn_s_barrier();
        compute(cur, acc);
        if (t + 2 < 32) stage((cur + 2) % 3, (t + 2) * 32);
        cur = (cur + 1) % 3;
    }
    asm volatile("s_waitcnt vmcnt(0)" ::: "memory");       // final tile
    __builtin_amdgcn_s_barrier();
    compute(cur, acc);

    #pragma unroll
    for (int ni = 0; ni < 8; ni++) {
        const int n = nBase + wn * 128 + ni * 16 + r;
        const float bn = bias[n];
        #pragma unroll
        for (int mi = 0; mi < 4; mi++) {
            #pragma unroll
            for (int qq = 0; qq < 4; qq++) {
                int m = mBase + wm * 64 + mi * 16 + g * 4 + qq;
                float val = (acc[mi][ni][qq] + bn) * oscale;
                int b = m >> 11, s = m & 2047;
                int hh = n >> 6, dd = n & 63;
                bf16_t bvv = (bf16_t)val;
                if constexpr (EPI == 0) {
                    Out[(((size_t)(b * NH + hh)) * S_LEN + s) * DKH + dd] = bvv;
                } else {
                    // key-permuted column: c = A^-1(s&63)
                    int o = s & 63;
                    int c2 = (o & 0x23) | (((o >> 3) & 1) << 4) | (((o >> 2) & 1) << 3)
                           | (((o >> 4) & 1) << 2);
                    int s2 = (s & ~63) | c2;
                    Out[(((size_t)(b * NH + hh)) * DKH + dd) * S_LEN + s2] = bvv;
                }
            }
        }
    }
}

// ---------------- O-projection GEMM: 128x256 tile, bf16 A, 3-deep counted vmcnt ----------------
__global__ __launch_bounds__(256) void gemm_o(const bf16_t* __restrict__ A,
                                              const bf16_t* __restrict__ B,
                                              const float* __restrict__ bias,
                                              float* __restrict__ Out) {
    __shared__ bf16_t As[3][128 * 32];    // 24 KB
    __shared__ bf16_t Bs[3][256 * 32];    // 48 KB

    const int d    = blockIdx.x;
    const int orig = (d & 7) * 32 + (d >> 3);
    const int mBase = (orig >> 2) * 128;
    const int nBase = (orig & 3) * 256;

    const int tid  = threadIdx.x;
    const int w    = tid >> 6;
    const int lane = tid & 63;
    const int g    = lane >> 4;
    const int r    = lane & 15;
    const int wm   = w >> 1, wn = w & 1;

    const int srow = lane >> 2;
    const int scol = (((lane & 3) ^ (srow & 3)) * 8);   // inverse-swizzled source slot

    auto stage = [&](int buf, int kt) {   // 6 gload16 per wave
        #pragma unroll
        for (int c = 0; c < 2; ++c) {
            const int row = w * 32 + c * 16;
            gload16(A + (size_t)(mBase + row + srow) * 1024 + kt + scol, &As[buf][row * 32]);
        }
        #pragma unroll
        for (int c = 0; c < 4; ++c) {
            const int row = w * 64 + c * 16;
            gload16(B + (size_t)(nBase + row + srow) * 1024 + kt + scol, &Bs[buf][row * 32]);
        }
    };

    auto compute = [&](int buf, f32x4 (*acc)[8]) {
        bf16x8 af[4], bfr[8];
        #pragma unroll
        for (int i = 0; i < 4; i++) {
            const int R = wm * 64 + i * 16 + r;
            af[i] = *(const bf16x8*)&As[buf][R * 32 + ((g ^ (R & 3)) * 8)];
        }
        #pragma unroll
        for (int i = 0; i < 8; i++) {
            const int R = wn * 128 + i * 16 + r;
            bfr[i] = *(const bf16x8*)&Bs[buf][R * 32 + ((g ^ (R & 3)) * 8)];
        }
        #pragma unroll
        for (int mi = 0; mi < 4; mi++)
            #pragma unroll
            for (int ni = 0; ni < 8; ni++)
                acc[mi][ni] = __builtin_amdgcn_mfma_f32_16x16x32_bf16(
                    af[mi], bfr[ni], acc[mi][ni], 0, 0, 0);
    };

    f32x4 acc[4][8] = {};

    stage(0, 0);
    stage(1, 32);

    int cur = 0;
    for (int t = 0; t < 31; ++t) {
        asm volatile("s_waitcnt vmcnt(6)" ::: "memory");
        __builtin_amdgcn_s_barrier();
        compute(cur, acc);
        if (t + 2 < 32) stage((cur + 2) % 3, (t + 2) * 32);
        cur = (cur + 1) % 3;
    }
    asm volatile("s_waitcnt vmcnt(0)" ::: "memory");
    __builtin_amdgcn_s_barrier();
    compute(cur, acc);

    #pragma unroll
    for (int ni = 0; ni < 8; ni++) {
        const int n = nBase + wn * 128 + ni * 16 + r;
        const float bn = bias[n];
        #pragma unroll
        for (int mi = 0; mi < 4; mi++) {
            #pragma unroll
            for (int qq = 0; qq < 4; qq++) {
                int m = mBase + wm * 64 + mi * 16 + g * 4 + qq;
                Out[(size_t)m * 1024 + n] = acc[mi][ni][qq] + bn;
            }
        }
    }
}

// ---------------- flash attention: 1024 blocks, one adjacent pair each (R13, proven 50.8us) ----------------
__device__ __forceinline__ void tile_softmax(f32x4 s[4], bool diag, int kbase, int qg,
                                             int g, bf16x8 pf[2]) {
    unsigned P32[8];
    #pragma unroll
    for (int ni = 0; ni < 4; ++ni) {
        float p[4];
        #pragma unroll
        for (int e = 0; e < 4; ++e) {
            float xx = s[ni][e];
            if (diag) {
                int kk = kbase + ni * 16 + g * 4 + e;
                if (kk > qg) xx = NEG_BIG;
            }
            p[e] = __builtin_amdgcn_exp2f(xx);
        }
        P32[2 * ni]     = pack2(p[0], p[1]);
        P32[2 * ni + 1] = pack2(p[2], p[3]);
    }
    union U { unsigned u[4]; bf16x8 v; } u0, u1;
    u0.u[0] = P32[0]; u0.u[1] = P32[1]; u0.u[2] = P32[2]; u0.u[3] = P32[3];
    u1.u[0] = P32[4]; u1.u[1] = P32[5]; u1.u[2] = P32[6]; u1.u[3] = P32[7];
    pf[0] = u0.v;
    pf[1] = u1.v;
}

__global__ __launch_bounds__(256) void attn9_kernel(const bf16_t* __restrict__ Qh,
                                                    const bf16_t* __restrict__ Kh,
                                                    const bf16_t* __restrict__ Vt,
                                                    bf16_t* __restrict__ Out) {
    __shared__ bf16_t KV[2][2][64][64];   // 32768 B, XOR-swizzled 16B slots

    const int j   = blockIdx.x;
    const int c   = j >> 8;
    const int rem = j & 255;
    const int y   = rem >> 6;
    const int bh  = rem & 63;
    const int p   = (c == 0) ? y : (c == 1) ? 15 - y : (c == 2) ? 4 + y : 11 - y;

    const int b   = bh >> 4, h = bh & 15;
    const int tid = threadIdx.x;
    const int w    = tid >> 6;
    const int lane = tid & 63;
    const int g    = lane >> 4;
    const int r    = lane & 15;

    const int qtA = 2 * p, qtB = 2 * p + 1, last = qtB;

    const bf16_t* Qg = Qh + (size_t)bh * S_LEN * DKH;
    const bf16_t* Kg = Kh + (size_t)bh * S_LEN * DKH;
    const bf16_t* Vg = Vt + (size_t)bh * DKH * S_LEN;

    const int qA = qtA * 64 + w * 16 + r;
    const int qB = qtB * 64 + w * 16 + r;

    bf16x8 qfA[2], qfB[2];
    #pragma unroll
    for (int hh = 0; hh < 2; ++hh) {
        qfA[hh] = *(const bf16x8*)(Qg + (size_t)qA * DKH + hh * 32 + g * 8);
        qfB[hh] = *(const bf16x8*)(Qg + (size_t)qB * DKH + hh * 32 + g * 8);
    }

    bf16x8 ones;
    #pragma unroll
    for (int jj = 0; jj < 8; ++jj) ones[jj] = (bf16_t)1.0f;

    auto stage = [&](int buf, int kt) {
        #pragma unroll
        for (int cc = 0; cc < 2; ++cc) {
            const int row = w * 16 + cc * 8 + (lane >> 3);
            const int sl  = (lane & 7) ^ (row & 7);
            gload16(Kg + ((size_t)(kt * 64 + row)) * DKH + sl * 8,
                    (char*)&KV[buf][0][0][0] + w * 2048 + cc * 1024);
            gload16(Vg + (size_t)row * S_LEN + kt * 64 + sl * 8,
                    (char*)&KV[buf][1][0][0] + w * 2048 + cc * 1024);
        }
    };

    f32x4 oA[4] = {}, oB[4] = {};
    f32x4 lA4 = {}, lB4 = {};

    stage(0, 0);
    asm volatile("s_waitcnt vmcnt(0)" ::: "memory");
    __builtin_amdgcn_s_barrier();

    for (int kt = 0; kt <= last; ++kt) {
        const int buf = kt & 1;
        if (kt < last) stage(buf ^ 1, kt + 1);

        bf16x8 kf[4][2];
        #pragma unroll
        for (int ni = 0; ni < 4; ++ni) {
            const int row = ni * 16 + r;
            const char* base = (const char*)&KV[buf][0][0][0] + (row << 7);
            kf[ni][0] = *(const bf16x8*)(base + (((0 + g) ^ (row & 7)) << 4));
            kf[ni][1] = *(const bf16x8*)(base + (((4 + g) ^ (row & 7)) << 4));
        }

        const bool actA = (kt <= qtA);
        bf16x8 pfA[2], pfB[2];

        if (actA) {
            f32x4 s[4] = {};
            __builtin_amdgcn_s_setprio(1);
            #pragma unroll
            for (int ni = 0; ni < 4; ++ni) {
                s[ni] = __builtin_amdgcn_mfma_f32_16x16x32_bf16(kf[ni][0], qfA[0], s[ni], 0, 0, 0);
                s[ni] = __builtin_amdgcn_mfma_f32_16x16x32_bf16(kf[ni][1], qfA[1], s[ni], 0, 0, 0);
            }
            __builtin_amdgcn_s_setprio(0);
            tile_softmax(s, kt == qtA, kt * 64, qA, g, pfA);
        }
        {
            f32x4 s[4] = {};
            __builtin_amdgcn_s_setprio(1);
            #pragma unroll
            for (int ni = 0; ni < 4; ++ni) {
                s[ni] = __builtin_amdgcn_mfma_f32_16x16x32_bf16(kf[ni][0], qfB[0], s[ni], 0, 0, 0);
                s[ni] = __builtin_amdgcn_mfma_f32_16x16x32_bf16(kf[ni][1], qfB[1], s[ni], 0, 0, 0);
            }
            __builtin_amdgcn_s_setprio(0);
            tile_softmax(s, kt == qtB, kt * 64, qB, g, pfB);
        }

        __builtin_amdgcn_s_setprio(1);
        #pragma unroll
        for (int ndi = 0; ndi < 4; ++ndi) {
            const int row = ndi * 16 + r;
            const char* base = (const char*)&KV[buf][1][0][0] + (row << 7);
            bf16x8 v0 = *(const bf16x8*)(base + (((0 + g) ^ (row & 7)) << 4));
            bf16x8 v1 = *(const bf16x8*)(base + (((4 + g) ^ (row & 7)) << 4));
            if (actA) {
                oA[ndi] = __builtin_amdgcn_mfma_f32_16x16x32_bf16(v0, pfA[0], oA[ndi], 0, 0, 0);
                oA[ndi] = __builtin_amdgcn_mfma_f32_16x16x32_bf16(v1, pfA[1], oA[ndi], 0, 0, 0);
            }
            oB[ndi] = __builtin_amdgcn_mfma_f32_16x16x32_bf16(v0, pfB[0], oB[ndi], 0, 0, 0);
            oB[ndi] = __builtin_amdgcn_mfma_f32_16x16x32_bf16(v1, pfB[1], oB[ndi], 0, 0, 0);
        }
        if (actA) {
            lA4 = __builtin_amdgcn_mfma_f32_16x16x32_bf16(ones, pfA[0], lA4, 0, 0, 0);
            lA4 = __builtin_amdgcn_mfma_f32_16x16x32_bf16(ones, pfA[1], lA4, 0, 0, 0);
        }
        lB4 = __builtin_amdgcn_mfma_f32_16x16x32_bf16(ones, pfB[0], lB4, 0, 0, 0);
        lB4 = __builtin_amdgcn_mfma_f32_16x16x32_bf16(ones, pfB[1], lB4, 0, 0, 0);
        __builtin_amdgcn_s_setprio(0);

        asm volatile("s_waitcnt vmcnt(0)" ::: "memory");
        __builtin_amdgcn_s_barrier();
    }

    const float invA = 1.0f / lA4[0], invB = 1.0f / lB4[0];
    bf16_t* OutA = Out + ((size_t)(b * S_LEN + qA)) * DM + h * DKH;
    bf16_t* OutB = Out + ((size_t)(b * S_LEN + qB)) * DM + h * DKH;
    #pragma unroll
    for (int ndi = 0; ndi < 4; ++ndi) {
        bf16x4 pa, pb;
        #pragma unroll
        for (int e = 0; e < 4; ++e) {
            pa[e] = (bf16_t)(oA[ndi][e] * invA);
            pb[e] = (bf16_t)(oB[ndi][e] * invB);
        }
        *(bf16x4*)(OutA + ndi * 16 + g * 4) = pa;
        *(bf16x4*)(OutB + ndi * 16 + g * 4) = pb;
    }
}

extern "C" void kernel_launch(void* const* d_in, const int* in_sizes, int n_in,
                              void* d_out, int out_size, void* d_ws, size_t ws_size,
                              hipStream_t stream) {
    const float* q  = (const float*)d_in[0];
    const float* k  = (const float*)d_in[1];
    const float* v  = (const float*)d_in[2];
    const float* wq = (const float*)d_in[4];
    const float* bq = (const float*)d_in[5];
    const float* wk = (const float*)d_in[6];
    const float* bk = (const float*)d_in[7];
    const float* wv = (const float*)d_in[8];
    const float* bv = (const float*)d_in[9];
    const float* wo = (const float*)d_in[10];
    const float* bo = (const float*)d_in[11];
    float* out = (float*)d_out;

    bf16_t* ws   = (bf16_t*)d_ws;
    bf16_t* Wq   = ws;
    bf16_t* Wk   = Wq + (1 << 20);
    bf16_t* Wv   = Wk + (1 << 20);
    bf16_t* Wo   = Wv + (1 << 20);
    bf16_t* Qh   = Wo + (1 << 20);
    bf16_t* Kh   = Qh + (8 << 20);
    bf16_t* Vt   = Kh + (8 << 20);
    bf16_t* attn = Vt + (8 << 20);

    cvt4_w<<<dim3(1024, 4), 256, 0, stream>>>(wq, wk, wv, wo, Wq, Wk, Wv, Wo);

    gemm_proj<0><<<256, 256, 0, stream>>>(q, Wq, bq, Qh, QSCALE);
    gemm_proj<0><<<256, 256, 0, stream>>>(k, Wk, bk, Kh, 1.0f);
    gemm_proj<1><<<256, 256, 0, stream>>>(v, Wv, bv, Vt, 1.0f);

    attn9_kernel<<<1024, 256, 0, stream>>>(Qh, Kh, Vt, attn);

    gemm_o<<<256, 256, 0, stream>>>(attn, Wo, bo, out);
}

// Round 22
// 163.798 us; speedup vs baseline: 1.1423x; 1.1423x over previous
//
#include <hip/hip_runtime.h>
#include <hip/hip_bf16.h>
#include <math.h>

#define S_LEN 2048
#define DM    1024
#define NH    16
#define DKH   64
#define NEG_BIG (-1e30f)
// 1/sqrt(64) * log2(e), folded into Q projection so softmax runs in exp2 domain
#define QSCALE 0.18033688f

typedef __bf16 bf16_t;
typedef bf16_t bf16x8 __attribute__((ext_vector_type(8)));
typedef bf16_t bf16x4 __attribute__((ext_vector_type(4)));
typedef bf16_t bf16x2 __attribute__((ext_vector_type(2)));
typedef float  f32x4  __attribute__((ext_vector_type(4)));

__device__ __forceinline__ void gload16(const void* g, void* l) {
    __builtin_amdgcn_global_load_lds((const __attribute__((address_space(1))) void*)g,
                                     (__attribute__((address_space(3))) void*)l, 16, 0, 0);
}

__device__ __forceinline__ unsigned pack2(float a, float b) {
    bf16x2 v; v[0] = (bf16_t)a; v[1] = (bf16_t)b;
    return __builtin_bit_cast(unsigned, v);
}

__device__ __forceinline__ bf16x8 cvt8v(f32x4 a, f32x4 b) {
    bf16x8 v;
    v[0] = (bf16_t)a[0]; v[1] = (bf16_t)a[1]; v[2] = (bf16_t)a[2]; v[3] = (bf16_t)a[3];
    v[4] = (bf16_t)b[0]; v[5] = (bf16_t)b[1]; v[6] = (bf16_t)b[2]; v[7] = (bf16_t)b[3];
    return v;
}

// ---------------- weights fp32 -> bf16 (one launch, 4 matrices) ----------------
__global__ __launch_bounds__(256) void cvt4_w(const float* __restrict__ w0, const float* __restrict__ w1,
                                              const float* __restrict__ w2, const float* __restrict__ w3,
                                              bf16_t* __restrict__ o0, bf16_t* __restrict__ o1,
                                              bf16_t* __restrict__ o2, bf16_t* __restrict__ o3) {
    const float* in; bf16_t* out;
    switch (blockIdx.y) {
        case 0: in = w0; out = o0; break;
        case 1: in = w1; out = o1; break;
        case 2: in = w2; out = o2; break;
        default: in = w3; out = o3; break;
    }
    int i = (blockIdx.x * 256 + threadIdx.x) * 4;
    float4 f = *(const float4*)(in + i);
    bf16x4 v;
    v[0] = (bf16_t)f.x; v[1] = (bf16_t)f.y; v[2] = (bf16_t)f.z; v[3] = (bf16_t)f.w;
    *(bf16x4*)(out + i) = v;
}

// ---------------- projection GEMM: fp32-A, 3-deep LDS pipeline, COUNTED vmcnt (T4) ----------------
// AsF: XOR-swizzled 16B slots (^row&7). Bs: slot^(row&3) swizzle. Stage after compute.
// EPI 0: bf16 [b,h,s,d] * oscale | EPI 1: bf16 [b,h,d,s] with key-permutation A^-1
template<int EPI>
__global__ __launch_bounds__(256) void gemm_proj(const float* __restrict__ Af,
                                                 const bf16_t* __restrict__ B,
                                                 const float* __restrict__ bias,
                                                 bf16_t* __restrict__ Out,
                                                 float oscale) {
    __shared__ float  AsF[3][128 * 32];   // 3 x 16 KB fp32 A tiles
    __shared__ bf16_t Bs[3][128 * 32];    // 3 x 8 KB

    const int d    = blockIdx.x;                 // XCD = d % 8
    const int orig = (d & 7) * 64 + (d >> 3);    // orig = mB*8 + nB
    const int mBase = (orig >> 3) * 128;
    const int nBase = (orig & 7) * 128;

    const int tid  = threadIdx.x;
    const int w    = tid >> 6;
    const int lane = tid & 63;
    const int g    = lane >> 4;
    const int r    = lane & 15;
    const int wm   = w >> 1, wn = w & 1;

    const int srow = lane >> 2;
    const int scolB = (((lane & 3) ^ (srow & 3)) * 8);   // inverse-swizzled B source slot
    const int frow = lane >> 3;
    const int fsl  = (lane & 7) ^ (frow & 7);

    auto stage = [&](int buf, int kt) {   // 6 gload16 per wave
        #pragma unroll
        for (int c = 0; c < 4; ++c) {
            const int row = w * 32 + c * 8;
            gload16(Af + (size_t)(mBase + row + frow) * 1024 + kt + fsl * 4, &AsF[buf][row * 32]);
        }
        #pragma unroll
        for (int c = 0; c < 2; ++c) {
            const int row = w * 32 + c * 16;
            gload16(B + (size_t)(nBase + row + srow) * 1024 + kt + scolB, &Bs[buf][row * 32]);
        }
    };

    auto compute = [&](int buf, f32x4 (*acc)[4]) {
        bf16x8 af[4], bfr[4];
        #pragma unroll
        for (int i = 0; i < 4; i++) {
            const int R = wm * 64 + i * 16 + r;
            const float* rb = &AsF[buf][R * 32];
            f32x4 f0 = *(const f32x4*)(rb + (((2 * g) ^ (r & 7)) << 2));
            f32x4 f1 = *(const f32x4*)(rb + (((2 * g + 1) ^ (r & 7)) << 2));
            af[i] = cvt8v(f0, f1);
        }
        #pragma unroll
        for (int i = 0; i < 4; i++) {
            const int R = wn * 64 + i * 16 + r;
            bfr[i] = *(const bf16x8*)&Bs[buf][R * 32 + ((g ^ (R & 3)) * 8)];
        }
        #pragma unroll
        for (int mi = 0; mi < 4; mi++)
            #pragma unroll
            for (int ni = 0; ni < 4; ni++)
                acc[mi][ni] = __builtin_amdgcn_mfma_f32_16x16x32_bf16(
                    af[mi], bfr[ni], acc[mi][ni], 0, 0, 0);
    };

    f32x4 acc[4][4] = {};

    stage(0, 0);
    stage(1, 32);

    int cur = 0;
    for (int t = 0; t < 31; ++t) {
        asm volatile("s_waitcnt vmcnt(6)" ::: "memory");   // stage t landed; t+1 in flight
        __builtin_amdgcn_s_barrier();
        compute(cur, acc);
        if (t + 2 < 32) stage((cur + 2) % 3, (t + 2) * 32);
        cur = (cur + 1) % 3;
    }
    asm volatile("s_waitcnt vmcnt(0)" ::: "memory");       // final tile
    __builtin_amdgcn_s_barrier();
    compute(cur, acc);

    #pragma unroll
    for (int ni = 0; ni < 4; ni++) {
        const int n = nBase + wn * 64 + ni * 16 + r;
        const float bn = bias[n];
        #pragma unroll
        for (int mi = 0; mi < 4; mi++) {
            #pragma unroll
            for (int qq = 0; qq < 4; qq++) {
                int m = mBase + wm * 64 + mi * 16 + g * 4 + qq;
                float val = (acc[mi][ni][qq] + bn) * oscale;
                int b = m >> 11, s = m & 2047;
                int hh = n >> 6, dd = n & 63;
                bf16_t bvv = (bf16_t)val;
                if constexpr (EPI == 0) {
                    Out[(((size_t)(b * NH + hh)) * S_LEN + s) * DKH + dd] = bvv;
                } else {
                    // key-permuted column: c = A^-1(s&63)
                    int o = s & 63;
                    int c2 = (o & 0x23) | (((o >> 3) & 1) << 4) | (((o >> 2) & 1) << 3)
                           | (((o >> 4) & 1) << 2);
                    int s2 = (s & ~63) | c2;
                    Out[(((size_t)(b * NH + hh)) * DKH + dd) * S_LEN + s2] = bvv;
                }
            }
        }
    }
}

// ---------------- O-projection GEMM (bf16 A, 3-deep pipeline, counted vmcnt) ----------------
__global__ __launch_bounds__(256) void gemm_o(const bf16_t* __restrict__ A,
                                              const bf16_t* __restrict__ B,
                                              const float* __restrict__ bias,
                                              float* __restrict__ Out) {
    __shared__ bf16_t As[3][128 * 32];
    __shared__ bf16_t Bs[3][128 * 32];

    const int d    = blockIdx.x;
    const int orig = (d & 7) * 64 + (d >> 3);
    const int mBase = (orig >> 3) * 128;
    const int nBase = (orig & 7) * 128;

    const int tid  = threadIdx.x;
    const int w    = tid >> 6;
    const int lane = tid & 63;
    const int g    = lane >> 4;
    const int r    = lane & 15;
    const int wm   = w >> 1, wn = w & 1;

    const int srow = lane >> 2;
    const int scol = (((lane & 3) ^ (srow & 3)) * 8);   // inverse-swizzled source slot

    auto stage = [&](int buf, int kt) {   // 4 gload16 per wave
        #pragma unroll
        for (int c = 0; c < 2; ++c) {
            const int row = w * 32 + c * 16;
            gload16(A + (size_t)(mBase + row + srow) * 1024 + kt + scol, &As[buf][row * 32]);
            gload16(B + (size_t)(nBase + row + srow) * 1024 + kt + scol, &Bs[buf][row * 32]);
        }
    };

    auto compute = [&](int buf, f32x4 (*acc)[4]) {
        bf16x8 af[4], bfr[4];
        #pragma unroll
        for (int i = 0; i < 4; i++) {
            const int R = wm * 64 + i * 16 + r;
            af[i] = *(const bf16x8*)&As[buf][R * 32 + ((g ^ (R & 3)) * 8)];
        }
        #pragma unroll
        for (int i = 0; i < 4; i++) {
            const int R = wn * 64 + i * 16 + r;
            bfr[i] = *(const bf16x8*)&Bs[buf][R * 32 + ((g ^ (R & 3)) * 8)];
        }
        #pragma unroll
        for (int mi = 0; mi < 4; mi++)
            #pragma unroll
            for (int ni = 0; ni < 4; ni++)
                acc[mi][ni] = __builtin_amdgcn_mfma_f32_16x16x32_bf16(
                    af[mi], bfr[ni], acc[mi][ni], 0, 0, 0);
    };

    f32x4 acc[4][4] = {};

    stage(0, 0);
    stage(1, 32);

    int cur = 0;
    for (int t = 0; t < 31; ++t) {
        asm volatile("s_waitcnt vmcnt(4)" ::: "memory");
        __builtin_amdgcn_s_barrier();
        compute(cur, acc);
        if (t + 2 < 32) stage((cur + 2) % 3, (t + 2) * 32);
        cur = (cur + 1) % 3;
    }
    asm volatile("s_waitcnt vmcnt(0)" ::: "memory");
    __builtin_amdgcn_s_barrier();
    compute(cur, acc);

    #pragma unroll
    for (int ni = 0; ni < 4; ni++) {
        const int n = nBase + wn * 64 + ni * 16 + r;
        const float bn = bias[n];
        #pragma unroll
        for (int mi = 0; mi < 4; mi++) {
            #pragma unroll
            for (int qq = 0; qq < 4; qq++) {
                int m = mBase + wm * 64 + mi * 16 + g * 4 + qq;
                Out[(size_t)m * 1024 + n] = acc[mi][ni][qq] + bn;
            }
        }
    }
}

// ---------------- flash attention: 1024 blocks, one adjacent pair each (proven 50.8us) ----------------
__device__ __forceinline__ void tile_softmax(f32x4 s[4], bool diag, int kbase, int qg,
                                             int g, bf16x8 pf[2]) {
    unsigned P32[8];
    #pragma unroll
    for (int ni = 0; ni < 4; ++ni) {
        float p[4];
        #pragma unroll
        for (int e = 0; e < 4; ++e) {
            float xx = s[ni][e];
            if (diag) {
                int kk = kbase + ni * 16 + g * 4 + e;
                if (kk > qg) xx = NEG_BIG;
            }
            p[e] = __builtin_amdgcn_exp2f(xx);
        }
        P32[2 * ni]     = pack2(p[0], p[1]);
        P32[2 * ni + 1] = pack2(p[2], p[3]);
    }
    union U { unsigned u[4]; bf16x8 v; } u0, u1;
    u0.u[0] = P32[0]; u0.u[1] = P32[1]; u0.u[2] = P32[2]; u0.u[3] = P32[3];
    u1.u[0] = P32[4]; u1.u[1] = P32[5]; u1.u[2] = P32[6]; u1.u[3] = P32[7];
    pf[0] = u0.v;
    pf[1] = u1.v;
}

__global__ __launch_bounds__(256) void attn9_kernel(const bf16_t* __restrict__ Qh,
                                                    const bf16_t* __restrict__ Kh,
                                                    const bf16_t* __restrict__ Vt,
                                                    bf16_t* __restrict__ Out) {
    __shared__ bf16_t KV[2][2][64][64];   // 32768 B, XOR-swizzled 16B slots

    const int j   = blockIdx.x;
    const int c   = j >> 8;
    const int rem = j & 255;
    const int y   = rem >> 6;
    const int bh  = rem & 63;
    const int p   = (c == 0) ? y : (c == 1) ? 15 - y : (c == 2) ? 4 + y : 11 - y;

    const int b   = bh >> 4, h = bh & 15;
    const int tid = threadIdx.x;
    const int w    = tid >> 6;
    const int lane = tid & 63;
    const int g    = lane >> 4;
    const int r    = lane & 15;

    const int qtA = 2 * p, qtB = 2 * p + 1, last = qtB;

    const bf16_t* Qg = Qh + (size_t)bh * S_LEN * DKH;
    const bf16_t* Kg = Kh + (size_t)bh * S_LEN * DKH;
    const bf16_t* Vg = Vt + (size_t)bh * DKH * S_LEN;

    const int qA = qtA * 64 + w * 16 + r;
    const int qB = qtB * 64 + w * 16 + r;

    bf16x8 qfA[2], qfB[2];
    #pragma unroll
    for (int hh = 0; hh < 2; ++hh) {
        qfA[hh] = *(const bf16x8*)(Qg + (size_t)qA * DKH + hh * 32 + g * 8);
        qfB[hh] = *(const bf16x8*)(Qg + (size_t)qB * DKH + hh * 32 + g * 8);
    }

    bf16x8 ones;
    #pragma unroll
    for (int jj = 0; jj < 8; ++jj) ones[jj] = (bf16_t)1.0f;

    auto stage = [&](int buf, int kt) {
        #pragma unroll
        for (int cc = 0; cc < 2; ++cc) {
            const int row = w * 16 + cc * 8 + (lane >> 3);
            const int sl  = (lane & 7) ^ (row & 7);
            gload16(Kg + ((size_t)(kt * 64 + row)) * DKH + sl * 8,
                    (char*)&KV[buf][0][0][0] + w * 2048 + cc * 1024);
            gload16(Vg + (size_t)row * S_LEN + kt * 64 + sl * 8,
                    (char*)&KV[buf][1][0][0] + w * 2048 + cc * 1024);
        }
    };

    f32x4 oA[4] = {}, oB[4] = {};
    f32x4 lA4 = {}, lB4 = {};

    stage(0, 0);
    asm volatile("s_waitcnt vmcnt(0)" ::: "memory");
    __builtin_amdgcn_s_barrier();

    for (int kt = 0; kt <= last; ++kt) {
        const int buf = kt & 1;
        if (kt < last) stage(buf ^ 1, kt + 1);

        bf16x8 kf[4][2];
        #pragma unroll
        for (int ni = 0; ni < 4; ++ni) {
            const int row = ni * 16 + r;
            const char* base = (const char*)&KV[buf][0][0][0] + (row << 7);
            kf[ni][0] = *(const bf16x8*)(base + (((0 + g) ^ (row & 7)) << 4));
            kf[ni][1] = *(const bf16x8*)(base + (((4 + g) ^ (row & 7)) << 4));
        }

        const bool actA = (kt <= qtA);
        bf16x8 pfA[2], pfB[2];

        if (actA) {
            f32x4 s[4] = {};
            __builtin_amdgcn_s_setprio(1);
            #pragma unroll
            for (int ni = 0; ni < 4; ++ni) {
                s[ni] = __builtin_amdgcn_mfma_f32_16x16x32_bf16(kf[ni][0], qfA[0], s[ni], 0, 0, 0);
                s[ni] = __builtin_amdgcn_mfma_f32_16x16x32_bf16(kf[ni][1], qfA[1], s[ni], 0, 0, 0);
            }
            __builtin_amdgcn_s_setprio(0);
            tile_softmax(s, kt == qtA, kt * 64, qA, g, pfA);
        }
        {
            f32x4 s[4] = {};
            __builtin_amdgcn_s_setprio(1);
            #pragma unroll
            for (int ni = 0; ni < 4; ++ni) {
                s[ni] = __builtin_amdgcn_mfma_f32_16x16x32_bf16(kf[ni][0], qfB[0], s[ni], 0, 0, 0);
                s[ni] = __builtin_amdgcn_mfma_f32_16x16x32_bf16(kf[ni][1], qfB[1], s[ni], 0, 0, 0);
            }
            __builtin_amdgcn_s_setprio(0);
            tile_softmax(s, kt == qtB, kt * 64, qB, g, pfB);
        }

        __builtin_amdgcn_s_setprio(1);
        #pragma unroll
        for (int ndi = 0; ndi < 4; ++ndi) {
            const int row = ndi * 16 + r;
            const char* base = (const char*)&KV[buf][1][0][0] + (row << 7);
            bf16x8 v0 = *(const bf16x8*)(base + (((0 + g) ^ (row & 7)) << 4));
            bf16x8 v1 = *(const bf16x8*)(base + (((4 + g) ^ (row & 7)) << 4));
            if (actA) {
                oA[ndi] = __builtin_amdgcn_mfma_f32_16x16x32_bf16(v0, pfA[0], oA[ndi], 0, 0, 0);
                oA[ndi] = __builtin_amdgcn_mfma_f32_16x16x32_bf16(v1, pfA[1], oA[ndi], 0, 0, 0);
            }
            oB[ndi] = __builtin_amdgcn_mfma_f32_16x16x32_bf16(v0, pfB[0], oB[ndi], 0, 0, 0);
            oB[ndi] = __builtin_amdgcn_mfma_f32_16x16x32_bf16(v1, pfB[1], oB[ndi], 0, 0, 0);
        }
        if (actA) {
            lA4 = __builtin_amdgcn_mfma_f32_16x16x32_bf16(ones, pfA[0], lA4, 0, 0, 0);
            lA4 = __builtin_amdgcn_mfma_f32_16x16x32_bf16(ones, pfA[1], lA4, 0, 0, 0);
        }
        lB4 = __builtin_amdgcn_mfma_f32_16x16x32_bf16(ones, pfB[0], lB4, 0, 0, 0);
        lB4 = __builtin_amdgcn_mfma_f32_16x16x32_bf16(ones, pfB[1], lB4, 0, 0, 0);
        __builtin_amdgcn_s_setprio(0);

        asm volatile("s_waitcnt vmcnt(0)" ::: "memory");
        __builtin_amdgcn_s_barrier();
    }

    const float invA = 1.0f / lA4[0], invB = 1.0f / lB4[0];
    bf16_t* OutA = Out + ((size_t)(b * S_LEN + qA)) * DM + h * DKH;
    bf16_t* OutB = Out + ((size_t)(b * S_LEN + qB)) * DM + h * DKH;
    #pragma unroll
    for (int ndi = 0; ndi < 4; ++ndi) {
        bf16x4 pa, pb;
        #pragma unroll
        for (int e = 0; e < 4; ++e) {
            pa[e] = (bf16_t)(oA[ndi][e] * invA);
            pb[e] = (bf16_t)(oB[ndi][e] * invB);
        }
        *(bf16x4*)(OutA + ndi * 16 + g * 4) = pa;
        *(bf16x4*)(OutB + ndi * 16 + g * 4) = pb;
    }
}

extern "C" void kernel_launch(void* const* d_in, const int* in_sizes, int n_in,
                              void* d_out, int out_size, void* d_ws, size_t ws_size,
                              hipStream_t stream) {
    const float* q  = (const float*)d_in[0];
    const float* k  = (const float*)d_in[1];
    const float* v  = (const float*)d_in[2];
    const float* wq = (const float*)d_in[4];
    const float* bq = (const float*)d_in[5];
    const float* wk = (const float*)d_in[6];
    const float* bk = (const float*)d_in[7];
    const float* wv = (const float*)d_in[8];
    const float* bv = (const float*)d_in[9];
    const float* wo = (const float*)d_in[10];
    const float* bo = (const float*)d_in[11];
    float* out = (float*)d_out;

    bf16_t* ws   = (bf16_t*)d_ws;
    bf16_t* Wq   = ws;
    bf16_t* Wk   = Wq + (1 << 20);
    bf16_t* Wv   = Wk + (1 << 20);
    bf16_t* Wo   = Wv + (1 << 20);
    bf16_t* Qh   = Wo + (1 << 20);
    bf16_t* Kh   = Qh + (8 << 20);
    bf16_t* Vt   = Kh + (8 << 20);
    bf16_t* attn = Vt + (8 << 20);

    cvt4_w<<<dim3(1024, 4), 256, 0, stream>>>(wq, wk, wv, wo, Wq, Wk, Wv, Wo);

    gemm_proj<0><<<512, 256, 0, stream>>>(q, Wq, bq, Qh, QSCALE);
    gemm_proj<0><<<512, 256, 0, stream>>>(k, Wk, bk, Kh, 1.0f);
    gemm_proj<1><<<512, 256, 0, stream>>>(v, Wv, bv, Vt, 1.0f);

    attn9_kernel<<<1024, 256, 0, stream>>>(Qh, Kh, Vt, attn);

    gemm_o<<<512, 256, 0, stream>>>(attn, Wo, bo, out);
}